// Round 15
// baseline (268.520 us; speedup 1.0000x reference)
//
#include <hip/hip_runtime.h>
#include <cstdint>
#include <cstddef>

// GLA forward, bf16 MFMA pipeline: 2-slot counted-vmcnt loop, XOR-swizzled LDS,
// coalesced LDS-roundtrip epilogues; v emitted transposed from proj.
// r15: gate_cum re-gridded 512x64 (was on half the CUs), x-cast fused into
// lowrank1, intra_k two GEMM phases fused into one pipeline.
// B=2, T=2048, D=1024, H=4, HK=256, HV=512, DK=1024, DV=2048, LR=16, CHUNK=128

typedef unsigned short u16;
typedef __attribute__((ext_vector_type(8))) short s8v;   // 8 x bf16 (4 VGPR)
typedef __attribute__((ext_vector_type(4))) short s4v;   // 4 x bf16 (8B)
typedef __attribute__((ext_vector_type(4))) float f4v;   // MFMA accumulator

__device__ __forceinline__ u16 f2b(float f) {
  unsigned u = __builtin_bit_cast(unsigned, f);
  unsigned r = u + 0x7FFFu + ((u >> 16) & 1u);   // RNE
  return (u16)(r >> 16);
}
__device__ __forceinline__ float b2f(u16 h) {
  unsigned u = ((unsigned)h) << 16;
  return __builtin_bit_cast(float, u);
}

// async global->LDS, 16B per lane; LDS dest is wave-uniform base + lane*16
__device__ __forceinline__ void cp16(const void* g, void* l) {
  __builtin_amdgcn_global_load_lds(
      (const __attribute__((address_space(1))) unsigned int*)g,
      (__attribute__((address_space(3))) unsigned int*)l, 16, 0, 0);
}

// ---- shared MFMA core: C[128x128] += A[128xK] * BT[128xK]^T, bf16, BK=32 ----
__device__ __forceinline__ void stage_tile(const u16* g, int ld, u16* lds,
                                           int wv, int ln) {
  const int q = (ln & 3) ^ ((ln >> 3) & 3);
#pragma unroll
  for (int i = 0; i < 2; ++i) {
    const int c = wv * 2 + i;                       // 1KB chunk id 0..7
    const u16* src = g + (size_t)(c * 16 + (ln >> 2)) * ld + q * 8;
    cp16(src, lds + c * 512);
  }
}

__device__ __forceinline__ void gemm_core(
    const u16* __restrict__ A, int lda, const u16* __restrict__ BT, int ldb,
    int K, u16* As, u16* Bs, f4v acc[4][4])
{
  const int tid = threadIdx.x;
  const int ln = tid & 63, wv = tid >> 6;
  const int arow = (wv >> 1) * 64 + (ln & 15);
  const int brow = (wv & 1) * 64 + (ln & 15);
  const int koff = (((ln >> 4) ^ ((ln >> 1) & 3)) * 8);
  const int nt = K >> 5;
  stage_tile(A, lda, As, wv, ln);
  stage_tile(BT, ldb, Bs, wv, ln);
  stage_tile(A + 32, lda, As + 4096, wv, ln);
  stage_tile(BT + 32, ldb, Bs + 4096, wv, ln);
  int slot = 0;
  for (int t = 0; t < nt; ++t) {
    if (t + 1 < nt) asm volatile("s_waitcnt vmcnt(4)" ::: "memory");
    else            asm volatile("s_waitcnt vmcnt(0)" ::: "memory");
    __builtin_amdgcn_s_barrier();
    __builtin_amdgcn_sched_barrier(0);
    const u16* Ab = As + slot * 4096;
    const u16* Bb = Bs + slot * 4096;
    s8v af[4], bf[4];
#pragma unroll
    for (int f = 0; f < 4; ++f)
      af[f] = *(const s8v*)(Ab + (arow + f * 16) * 32 + koff);
#pragma unroll
    for (int f = 0; f < 4; ++f)
      bf[f] = *(const s8v*)(Bb + (brow + f * 16) * 32 + koff);
#pragma unroll
    for (int mf = 0; mf < 4; ++mf)
#pragma unroll
      for (int nf = 0; nf < 4; ++nf)
        acc[mf][nf] = __builtin_amdgcn_mfma_f32_16x16x32_bf16(
            af[mf], bf[nf], acc[mf][nf], 0, 0, 0);
    __builtin_amdgcn_sched_barrier(0);
    __builtin_amdgcn_s_barrier();
    if (t + 2 < nt) {
      stage_tile(A + (t + 2) * 32, lda, As + slot * 4096, wv, ln);
      stage_tile(BT + (t + 2) * 32, ldb, Bs + slot * 4096, wv, ln);
    }
    slot ^= 1;
  }
}

// ---- fused two-source core: C += A1*B1T (K1) then += A2*B2T (K2), one
// continuous pipeline (no mid-block drain). Same math as two gemm_core calls.
__device__ __forceinline__ void gemm_core2(
    const u16* __restrict__ A1, int lda1, const u16* __restrict__ B1, int ldb1,
    int K1,
    const u16* __restrict__ A2, int lda2, const u16* __restrict__ B2, int ldb2,
    int K2, u16* As, u16* Bs, f4v acc[4][4])
{
  const int tid = threadIdx.x;
  const int ln = tid & 63, wv = tid >> 6;
  const int arow = (wv >> 1) * 64 + (ln & 15);
  const int brow = (wv & 1) * 64 + (ln & 15);
  const int koff = (((ln >> 4) ^ ((ln >> 1) & 3)) * 8);
  const int nt1 = K1 >> 5;
  const int nt = nt1 + (K2 >> 5);
  auto stage_step = [&](int t, int slot) {
    if (t < nt1) {
      stage_tile(A1 + t * 32, lda1, As + slot * 4096, wv, ln);
      stage_tile(B1 + t * 32, ldb1, Bs + slot * 4096, wv, ln);
    } else {
      stage_tile(A2 + (t - nt1) * 32, lda2, As + slot * 4096, wv, ln);
      stage_tile(B2 + (t - nt1) * 32, ldb2, Bs + slot * 4096, wv, ln);
    }
  };
  stage_step(0, 0);
  stage_step(1, 1);
  int slot = 0;
  for (int t = 0; t < nt; ++t) {
    if (t + 1 < nt) asm volatile("s_waitcnt vmcnt(4)" ::: "memory");
    else            asm volatile("s_waitcnt vmcnt(0)" ::: "memory");
    __builtin_amdgcn_s_barrier();
    __builtin_amdgcn_sched_barrier(0);
    const u16* Ab = As + slot * 4096;
    const u16* Bb = Bs + slot * 4096;
    s8v af[4], bf[4];
#pragma unroll
    for (int f = 0; f < 4; ++f)
      af[f] = *(const s8v*)(Ab + (arow + f * 16) * 32 + koff);
#pragma unroll
    for (int f = 0; f < 4; ++f)
      bf[f] = *(const s8v*)(Bb + (brow + f * 16) * 32 + koff);
#pragma unroll
    for (int mf = 0; mf < 4; ++mf)
#pragma unroll
      for (int nf = 0; nf < 4; ++nf)
        acc[mf][nf] = __builtin_amdgcn_mfma_f32_16x16x32_bf16(
            af[mf], bf[nf], acc[mf][nf], 0, 0, 0);
    __builtin_amdgcn_sched_barrier(0);
    __builtin_amdgcn_s_barrier();
    if (t + 2 < nt) stage_step(t + 2, slot);
    slot ^= 1;
  }
}

// ---- epilogue: fragments -> LDS (bf16, row stride 72 = 16B aligned) --------
__device__ __forceinline__ void frag_to_lds(u16* S, const f4v acc[4][4],
                                            int ln, int wv) {
  u16* q = S + wv * 4608;
#pragma unroll
  for (int mf = 0; mf < 4; ++mf)
#pragma unroll
    for (int nf = 0; nf < 4; ++nf)
#pragma unroll
      for (int r = 0; r < 4; ++r)
        q[(mf * 16 + ((ln >> 4) << 2) + r) * 72 + nf * 16 + (ln & 15)] =
            f2b(acc[mf][nf][r]);
}

// Transposed: T(c,r) at quad((c>>6)<<1 | r>>6)*4608 + (c&63)*72 + (r&63).
__device__ __forceinline__ void frag_to_lds_T(u16* S, const f4v acc[4][4],
                                              int ln, int wv) {
  const int wr = wv >> 1, wc = wv & 1;
  u16* q = S + ((wc << 1) + wr) * 4608;
#pragma unroll
  for (int mf = 0; mf < 4; ++mf)
#pragma unroll
    for (int nf = 0; nf < 4; ++nf) {
      const int cl = nf * 16 + (ln & 15);
      const int rl = mf * 16 + ((ln >> 4) << 2);
      s4v o4;
#pragma unroll
      for (int r = 0; r < 4; ++r) o4[r] = (short)f2b(acc[mf][nf][r]);
      *(s4v*)(q + cl * 72 + rl) = o4;
    }
}

template <typename F>
__device__ __forceinline__ void epi_loop(u16* S, const f4v acc[4][4], F f) {
  const int tid = threadIdx.x;
  frag_to_lds(S, acc, tid & 63, tid >> 6);
  __syncthreads();
#pragma unroll
  for (int p = 0; p < 8; ++p) {
    const int r = p * 16 + (tid >> 4);
    const int c0 = (tid & 15) * 8;
    const int quad = ((r >> 6) << 1) + (c0 >> 6);
    s8v vv = *(const s8v*)(S + quad * 4608 + (r & 63) * 72 + (c0 & 63));
    f(r, c0, vv);
  }
}

// transposed variant: r is the ORIGINAL COLUMN, c0 the ORIGINAL ROW base.
template <typename F>
__device__ __forceinline__ void epi_loop_T(u16* S, const f4v acc[4][4], F f) {
  const int tid = threadIdx.x;
  frag_to_lds_T(S, acc, tid & 63, tid >> 6);
  __syncthreads();
#pragma unroll
  for (int p = 0; p < 8; ++p) {
    const int r = p * 16 + (tid >> 4);        // column index 0..127
    const int c0 = (tid & 15) * 8;            // row base 0..120
    const int quad = ((r >> 6) << 1) + (c0 >> 6);
    s8v vv = *(const s8v*)(S + quad * 4608 + (r & 63) * 72 + (c0 & 63));
    f(r, c0, vv);
  }
}

// -------- all 5 weight transposes (x-cast moved into lowrank1) --------------
__global__ __launch_bounds__(256) void castw_all(
    const float* __restrict__ Wq, const float* __restrict__ Wk,
    const float* __restrict__ Wv, const float* __restrict__ Wg,
    const float* __restrict__ Wo,
    u16* __restrict__ WTa, u16* __restrict__ WoT)
{
  __shared__ float t[32][33];
  const int wid = blockIdx.x;
  const float* src; u16* dst; int R, C, local;
  if (wid < 1024)      { src = Wq; dst = WTa;           R = 1024; C = 1024; local = wid; }
  else if (wid < 2048) { src = Wk; dst = WTa + 1048576; R = 1024; C = 1024; local = wid - 1024; }
  else if (wid < 4096) { src = Wv; dst = WTa + 2097152; R = 1024; C = 2048; local = wid - 2048; }
  else if (wid < 6144) { src = Wg; dst = WTa + 4194304; R = 1024; C = 2048; local = wid - 4096; }
  else                 { src = Wo; dst = WoT;           R = 2048; C = 1024; local = wid - 6144; }
  const int nx = C >> 5;
  const int c0 = (local % nx) * 32, r0 = (local / nx) * 32;
  const int lx = threadIdx.x & 31, ly = threadIdx.x >> 5;
#pragma unroll
  for (int i = 0; i < 32; i += 8)
    t[ly + i][lx] = src[(size_t)(r0 + ly + i) * C + c0 + lx];
  __syncthreads();
#pragma unroll
  for (int i = 0; i < 32; i += 8)
    dst[(size_t)(c0 + ly + i) * R + r0 + lx] = f2b(t[lx][ly + i]);
}

// kt [bh][2048][256] -> ktT [bh][256][2048]
__global__ __launch_bounds__(256) void trans_kt(
    const u16* __restrict__ kt, u16* __restrict__ ktT)
{
  __shared__ u16 t[32][33];
  const int id = blockIdx.x;                  // 4096
  const int z = id >> 9, local = id & 511;
  const int c0 = (local & 7) * 32, r0 = (local >> 3) * 32;
  const size_t boff = (size_t)z * 2048 * 256;
  const int lx = threadIdx.x & 31, ly = threadIdx.x >> 5;
#pragma unroll
  for (int i = 0; i < 32; i += 8)
    t[ly + i][lx] = kt[boff + (size_t)(r0 + ly + i) * 256 + c0 + lx];
  __syncthreads();
#pragma unroll
  for (int i = 0; i < 32; i += 8)
    ktT[boff + (size_t)(c0 + ly + i) * 2048 + r0 + lx] = t[lx][ly + i];
}

// ------- low-rank gate part 1: tmp[4096,16] = x @ w1; also casts x -> xb ----
// Thread (m, i) computes dot(x[m], w1[:,i]) and afterwards casts its own
// 64-element span x[m][i*64:(i+1)*64] (L1/L2-hot re-read) to bf16.
__global__ __launch_bounds__(256) void lowrank1(
    const float* __restrict__ x, const float* __restrict__ w1,
    float* __restrict__ tmp, u16* __restrict__ xb)
{
  const int idx = blockIdx.x * 256 + threadIdx.x;
  const int m = idx >> 4, i = idx & 15;
  const float* xr = x + (size_t)m * 1024;
  float acc = 0.f;
#pragma unroll 4
  for (int kk = 0; kk < 1024; kk += 4) {
    const float4 xv = *(const float4*)(xr + kk);
    acc = fmaf(xv.x, w1[(kk + 0) * 16 + i], acc);
    acc = fmaf(xv.y, w1[(kk + 1) * 16 + i], acc);
    acc = fmaf(xv.z, w1[(kk + 2) * 16 + i], acc);
    acc = fmaf(xv.w, w1[(kk + 3) * 16 + i], acc);
  }
  tmp[idx] = acc;
  const float* xs = xr + i * 64;
  u16* xo = xb + (size_t)m * 1024 + i * 64;
#pragma unroll
  for (int p = 0; p < 8; ++p) {
    const float4 a = *(const float4*)(xs + p * 8);
    const float4 b = *(const float4*)(xs + p * 8 + 4);
    s8v o8;
    o8[0] = (short)f2b(a.x); o8[1] = (short)f2b(a.y);
    o8[2] = (short)f2b(a.z); o8[3] = (short)f2b(a.w);
    o8[4] = (short)f2b(b.x); o8[5] = (short)f2b(b.y);
    o8[6] = (short)f2b(b.z); o8[7] = (short)f2b(b.w);
    *(s8v*)(xo + p * 8) = o8;
  }
}

// -------- gate cumsum -> bf16 decay factors dq = e^B, dk = e^-B; Dc = e^B_end
// 512 blocks x 64 threads (was 128x256 -> only half the CUs had work).
// grid (16, 32): x = h*4 + iquad, y = b*16 + c. One wave per block.
__global__ __launch_bounds__(64) void gate_cum(
    const float* __restrict__ tmp, const float* __restrict__ w2,
    const float* __restrict__ bias, u16* __restrict__ dq, u16* __restrict__ dk,
    float* __restrict__ Dc)
{
  __shared__ float ls_t[2048];   // tmp slice for this (b, c): 128 t x 16
  const int b = blockIdx.y >> 4, c = blockIdx.y & 15;
  const int h = blockIdx.x >> 2;
  const int iq = blockIdx.x & 3;
  const int lane = threadIdx.x;          // 0..63
  const int i = iq * 64 + lane;
  const int n = h * 256 + i;
  const int bh = b * 4 + h;
  const float* tp = tmp + ((size_t)(b * 2048 + c * 128)) * 16;
#pragma unroll
  for (int r = 0; r < 32; ++r) ls_t[r * 64 + lane] = tp[r * 64 + lane];
  __syncthreads();
  float w2c[16];
#pragma unroll
  for (int r = 0; r < 16; ++r) w2c[r] = w2[r * 1024 + n];
  const float bn = bias[n];
  const size_t base = ((size_t)bh * 2048 + c * 128) * 256 + i;
  float B = 0.f;
  for (int t = 0; t < 128; ++t) {
    float gl = bn;
    const float* tr = ls_t + t * 16;
#pragma unroll
    for (int r = 0; r < 16; ++r) gl = fmaf(tr[r], w2c[r], gl);
    const float ls = fminf(gl, 0.f) - log1pf(expf(-fabsf(gl)));
    B += ls * 0.0625f;
    const float eB = expf(B);
    dq[base + (size_t)t * 256] = f2b(eB);
    dk[base + (size_t)t * 256] = f2b(1.f / eB);
  }
  Dc[(bh * 16 + c) * 256 + i] = expf(B);
}

// ---------------- fused projections: xb[4096,1024] @ [Wq|Wk|Wv|Wg] ----------
// q/k: decay fused, row-major. v: written TRANSPOSED directly to vT[bh][j][t].
__global__ __launch_bounds__(256) void proj_all(
    const u16* __restrict__ xb, const u16* __restrict__ WT,
    const u16* __restrict__ dq, const u16* __restrict__ dk,
    u16* __restrict__ qt, u16* __restrict__ kt,
    u16* __restrict__ vT, u16* __restrict__ gpre)
{
  __shared__ __align__(16) u16 S[18432];
  u16* As = S; u16* Bs = S + 8192;
  // XCD-chunked swizzle, n-fast within XCD
  const int id = blockIdx.x;
  const int xcd = id & 7, jb = id >> 3;
  const int m0 = (jb / 6) * 128;
  const int n0 = (xcd * 6 + (jb % 6)) * 128;
  f4v acc[4][4];
#pragma unroll
  for (int zi = 0; zi < 4; ++zi)
#pragma unroll
    for (int zj = 0; zj < 4; ++zj) acc[zi][zj] = (f4v){0.f, 0.f, 0.f, 0.f};
  gemm_core(xb + (size_t)m0 * 1024, 1024, WT + (size_t)n0 * 1024, 1024, 1024,
            As, Bs, acc);
  const int bb = m0 >> 11;              // batch (tile is within one b)
  const int t0 = m0 & 2047;
  if (n0 < 1024) {
    epi_loop(S, acc, [&](int r, int c0, s8v vv) {
      const int t = t0 + r;
      const int n = n0 + c0;
      const int bh = bb * 4 + (n >> 8);
      const size_t off = ((size_t)bh * 2048 + t) * 256 + (n & 255);
      const s8v dv = *(const s8v*)(dq + off);
      s8v o8;
#pragma unroll
      for (int e = 0; e < 8; ++e)
        o8[e] = (short)f2b(b2f((u16)vv[e]) * 0.0625f * b2f((u16)dv[e]));
      *(s8v*)(qt + off) = o8;
    });
  } else if (n0 < 2048) {
    epi_loop(S, acc, [&](int r, int c0, s8v vv) {
      const int t = t0 + r;
      const int nn = n0 + c0 - 1024;
      const int bh = bb * 4 + (nn >> 8);
      const size_t off = ((size_t)bh * 2048 + t) * 256 + (nn & 255);
      const s8v dv = *(const s8v*)(dk + off);
      s8v o8;
#pragma unroll
      for (int e = 0; e < 8; ++e)
        o8[e] = (short)f2b(b2f((u16)vv[e]) * b2f((u16)dv[e]));
      *(s8v*)(kt + off) = o8;
    });
  } else if (n0 < 4096) {
    const int nn0 = n0 - 2048;
    const int bh = bb * 4 + (nn0 >> 9);
    const int jj0 = nn0 & 511;
    epi_loop_T(S, acc, [&](int r, int c0, s8v vv) {
      // r = column offset (j), c0 = row base (t)
      *(s8v*)(vT + ((size_t)(bh * 512 + jj0 + r)) * 2048 + t0 + c0) = vv;
    });
  } else {
    epi_loop(S, acc, [&](int r, int c0, s8v vv) {
      *(s8v*)(gpre + (size_t)(m0 + r) * 2048 + (n0 + c0 - 4096)) = vv;
    });
  }
}

// ------- merged scan GEMMs: x<8 -> chunk_state tile, x==8 -> qk_causal ------
__global__ __launch_bounds__(256) void scan_gemms(
    const u16* __restrict__ vT, const u16* __restrict__ ktT,
    const u16* __restrict__ qt, const u16* __restrict__ kt,
    u16* __restrict__ UT, u16* __restrict__ Aw)
{
  __shared__ __align__(16) u16 S[18432];
  u16* As = S; u16* Bs = S + 8192;
  const int bhc = blockIdx.y, bh = bhc >> 4, c = bhc & 15;
  f4v acc[4][4];
#pragma unroll
  for (int zi = 0; zi < 4; ++zi)
#pragma unroll
    for (int zj = 0; zj < 4; ++zj) acc[zi][zj] = (f4v){0.f, 0.f, 0.f, 0.f};
  if (blockIdx.x < 8) {
    const int mt = blockIdx.x >> 1, nt = blockIdx.x & 1;
    gemm_core(vT + ((size_t)bh * 512 + mt * 128) * 2048 + c * 128, 2048,
              ktT + ((size_t)bh * 256 + nt * 128) * 2048 + c * 128, 2048, 128,
              As, Bs, acc);
    epi_loop(S, acc, [&](int r, int c0, s8v vv) {
      const int j = mt * 128 + r;
      const int i = nt * 128 + c0;
      *(s8v*)(UT + (((size_t)(bh * 512 + j)) * 16 + c) * 256 + i) = vv;
    });
  } else {
    const size_t base = ((size_t)bh * 2048 + c * 128) * 256;
    gemm_core(qt + base, 256, kt + base, 256, 256, As, Bs, acc);
    u16* Ap = Aw + (size_t)bhc * 16384;
    epi_loop(S, acc, [&](int r, int c0, s8v vv) {
      s8v o8;
#pragma unroll
      for (int e = 0; e < 8; ++e)
        o8[e] = (c0 + e <= r) ? vv[e] : (short)0;
      *(s8v*)(Ap + r * 128 + c0) = o8;
    });
  }
}

// ------ serial inter-chunk scan, in place on UT (bf16, fp32 accum) ----------
__global__ __launch_bounds__(256) void state_scan(
    u16* __restrict__ UT, const float* __restrict__ Dc)
{
  const int blk = blockIdx.x;               // 4096 = bh*512 + j
  const int bh = blk >> 9, j = blk & 511;
  const int i = threadIdx.x;
  u16* Up = UT + ((size_t)(bh * 512 + j)) * 16 * 256 + i;
  const float* Dp = Dc + bh * 16 * 256 + i;
  float Sa = 0.f;
#pragma unroll
  for (int c = 0; c < 16; ++c) {
    const float u = b2f(Up[c * 256]);
    const float d = Dp[c * 256];
    Up[c * 256] = f2b(Sa);
    Sa = d * (Sa + u);
  }
}

// -------- ob = Aw @ V + qt @ S  (per bhc, 128-col tile of HV) ---------------
// Both GEMM phases run in ONE continuous staged pipeline (gemm_core2).
__global__ __launch_bounds__(256) void intra_k(
    const u16* __restrict__ Aw, const u16* __restrict__ qt,
    const u16* __restrict__ vT, const u16* __restrict__ UT, u16* __restrict__ ob)
{
  __shared__ __align__(16) u16 S[18432];
  u16* As = S; u16* Bs = S + 8192;
  const int jt = blockIdx.x;
  const int bhc = blockIdx.y, bh = bhc >> 4, c = bhc & 15;
  f4v acc[4][4];
#pragma unroll
  for (int zi = 0; zi < 4; ++zi)
#pragma unroll
    for (int zj = 0; zj < 4; ++zj) acc[zi][zj] = (f4v){0.f, 0.f, 0.f, 0.f};
  gemm_core2(Aw + (size_t)bhc * 16384, 128,
             vT + ((size_t)bh * 512 + jt * 128) * 2048 + c * 128, 2048, 128,
             qt + ((size_t)bh * 2048 + c * 128) * 256, 256,
             UT + ((size_t)(bh * 512 + jt * 128)) * 4096 + (size_t)c * 256,
             4096, 256, As, Bs, acc);
  const int b = bh >> 2, h = bh & 3;
  epi_loop(S, acc, [&](int r, int c0, s8v vv) {
    const int t = c * 128 + r;
    const int j = jt * 128 + c0;
    *(s8v*)(ob + ((size_t)(b * 2048 + t)) * 2048 + h * 512 + j) = vv;
  });
}

// ------- group RMSNorm (512) + SiLU gate, in place on ob (vectorized) -------
__global__ __launch_bounds__(256) void rms_silu(
    u16* __restrict__ o, const u16* __restrict__ gpre, const float* __restrict__ w)
{
  const int grp = blockIdx.x * 4 + (threadIdx.x >> 6);  // 16384 groups (b,t,h)
  const int lane = threadIdx.x & 63;
  const size_t base = (size_t)(grp >> 2) * 2048 + (grp & 3) * 512 + lane * 8;
  const s8v xv = *(const s8v*)(o + base);
  float xf[8];
  float ss = 0.f;
#pragma unroll
  for (int i = 0; i < 8; ++i) {
    xf[i] = b2f((u16)xv[i]);
    ss = fmaf(xf[i], xf[i], ss);
  }
#pragma unroll
  for (int off = 1; off < 64; off <<= 1) ss += __shfl_xor(ss, off, 64);
  const float r = rsqrtf(ss * (1.f / 512.f) + 1e-5f);
  const s8v gv = *(const s8v*)(gpre + base);
  const float4 w0 = *(const float4*)(w + lane * 8);
  const float4 w1 = *(const float4*)(w + lane * 8 + 4);
  const float wf[8] = {w0.x, w0.y, w0.z, w0.w, w1.x, w1.y, w1.z, w1.w};
  s8v o8;
#pragma unroll
  for (int i = 0; i < 8; ++i) {
    const float gp = b2f((u16)gv[i]);
    const float sig = 1.f / (1.f + expf(-gp));
    o8[i] = (short)f2b(xf[i] * r * wf[i] * gp * sig);
  }
  *(s8v*)(o + base) = o8;
}

// ---------------- final: out = ob @ Wo, split-K=2 into pout -----------------
__global__ __launch_bounds__(256) void gemm_out(
    const u16* __restrict__ ob, const u16* __restrict__ WoT,
    float* __restrict__ pout)
{
  __shared__ __align__(16) u16 S[18432];
  u16* As = S; u16* Bs = S + 8192;
  const int id = blockIdx.x;                 // 512 blocks, 64 per XCD
  const int wg = (id & 7) * 64 + (id >> 3);
  const int ks = wg >> 8;                    // K-half
  const int tt = wg & 255;
  const int m0 = (tt & 31) * 128, n0 = (tt >> 5) * 128;
  f4v acc[4][4];
#pragma unroll
  for (int zi = 0; zi < 4; ++zi)
#pragma unroll
    for (int zj = 0; zj < 4; ++zj) acc[zi][zj] = (f4v){0.f, 0.f, 0.f, 0.f};
  gemm_core(ob + (size_t)m0 * 2048 + ks * 1024, 2048,
            WoT + (size_t)n0 * 2048 + ks * 1024, 2048, 1024, As, Bs, acc);
  const int tid = threadIdx.x;
  const int ln = tid & 63, wv = tid >> 6;
  const int wr = wv >> 1, wc = wv & 1;
  float* po = pout + (size_t)ks * 4194304;
#pragma unroll
  for (int mf = 0; mf < 4; ++mf)
#pragma unroll
    for (int nf = 0; nf < 4; ++nf)
#pragma unroll
      for (int r = 0; r < 4; ++r) {
        const int m = m0 + wr * 64 + mf * 16 + ((ln >> 4) << 2) + r;
        const int n = n0 + wc * 64 + nf * 16 + (ln & 15);
        po[(size_t)m * 1024 + n] = acc[mf][nf][r];
      }
}

__global__ __launch_bounds__(256) void reduce_out(
    const float* __restrict__ p, float* __restrict__ out)
{
  const int i = blockIdx.x * 256 + threadIdx.x;   // float4 granularity
  const float4 a = ((const float4*)p)[i];
  const float4 b = ((const float4*)(p + 4194304))[i];
  ((float4*)out)[i] = make_float4(a.x + b.x, a.y + b.y, a.z + b.z, a.w + b.w);
}

extern "C" void kernel_launch(void* const* d_in, const int* in_sizes, int n_in,
                              void* d_out, int out_size, void* d_ws, size_t ws_size,
                              hipStream_t stream) {
  const float* x    = (const float*)d_in[0];
  const float* Wq   = (const float*)d_in[1];
  const float* Wk   = (const float*)d_in[2];
  const float* Wv   = (const float*)d_in[3];
  const float* Wg   = (const float*)d_in[4];
  const float* w1   = (const float*)d_in[5];
  const float* w2   = (const float*)d_in[6];
  const float* gb   = (const float*)d_in[7];
  const float* Wo   = (const float*)d_in[8];
  const float* rmsw = (const float*)d_in[9];
  float* out = (float*)d_out;

  char* W = (char*)d_ws;
  u16*   xb   = (u16*)W;   W += (size_t)8  << 20;   // [4096][1024]
  u16*   WTa  = (u16*)W;   W += (size_t)12 << 20;   // [6144][1024]
  u16*   WoT  = (u16*)W;   W += (size_t)4  << 20;   // [1024][2048]
  u16*   qt   = (u16*)W;   W += (size_t)8  << 20;   // [8][2048][256]
  u16*   kt   = (u16*)W;   W += (size_t)8  << 20;
  u16*   vT   = (u16*)W;   W += (size_t)16 << 20;   // [8][512][2048]
  u16*   ktT  = (u16*)W;   W += (size_t)8  << 20;   // [8][256][2048]
  u16*   gpre = (u16*)W;   W += (size_t)16 << 20;   // [4096][2048]
  float* tmp  = (float*)W; W += (size_t)256 << 10;  // [4096][16]
  float* Dc   = (float*)W; W += (size_t)128 << 10;  // [8][16][256]
  u16*   dq   = (u16*)W;   W += (size_t)8  << 20;   // [8][2048][256] bf16 e^B
  u16*   dk   = (u16*)W;   W += (size_t)8  << 20;   // e^-B
  u16*   UT   = (u16*)W;   W += (size_t)32 << 20;   // [8][512][16][256]
  u16*   Aw   = (u16*)W;   W += (size_t)4  << 20;   // [128][128][128]
  u16*   ob   = (u16*)W;   W += (size_t)16 << 20;   // [4096][2048]
  float* pout = (float*)W; W += (size_t)32 << 20;   // [2][4096][1024]

  // gate pipeline first (dq/dk needed by proj_all); lowrank1 also casts x->xb
  hipLaunchKernelGGL(lowrank1, dim3(256), dim3(256), 0, stream, x, w1, tmp, xb);
  hipLaunchKernelGGL(gate_cum, dim3(16, 32), dim3(64), 0, stream,
                     tmp, w2, gb, dq, dk, Dc);

  // weight transposes
  hipLaunchKernelGGL(castw_all, dim3(8192), dim3(256), 0, stream,
                     Wq, Wk, Wv, Wg, Wo, WTa, WoT);

  // fused q/k/v/g projections; v emitted transposed, decay fused
  hipLaunchKernelGGL(proj_all, dim3(1536), dim3(256), 0, stream,
                     xb, WTa, dq, dk, qt, kt, vT, gpre);

  // kt -> ktT (only remaining layout pass)
  hipLaunchKernelGGL(trans_kt, dim3(4096), dim3(256), 0, stream, kt, ktT);

  // chunked scan: (chunk_state || qk_causal) -> state_scan -> intra
  hipLaunchKernelGGL(scan_gemms, dim3(9, 128), dim3(256), 0, stream,
                     vT, ktT, qt, kt, UT, Aw);
  hipLaunchKernelGGL(state_scan, dim3(4096), dim3(256), 0, stream, UT, Dc);
  hipLaunchKernelGGL(intra_k, dim3(4, 128), dim3(256), 0, stream, Aw, qt, vT, UT, ob);

  // group RMSNorm + SiLU gate (in place), then output projection (split-K)
  hipLaunchKernelGGL(rms_silu, dim3(4096), dim3(256), 0, stream, ob, gpre, rmsw);
  hipLaunchKernelGGL(gemm_out, dim3(512), dim3(256), 0, stream, ob, WoT, pout);
  hipLaunchKernelGGL(reduce_out, dim3(4096), dim3(256), 0, stream, pout, out);
}

// Round 16
// 262.696 us; speedup vs baseline: 1.0222x; 1.0222x over previous
//
#include <hip/hip_runtime.h>
#include <cstdint>
#include <cstddef>

// GLA forward, bf16 MFMA pipeline: 2-slot counted-vmcnt loop, XOR-swizzled LDS,
// coalesced LDS-roundtrip epilogues; v emitted transposed from proj.
// Round-14 configuration (best measured: 259.8us). r15's triple fusion
// (gate_cum regrid / lowrank1+cast / gemm_core2) netted +9us -> reverted.
// B=2, T=2048, D=1024, H=4, HK=256, HV=512, DK=1024, DV=2048, LR=16, CHUNK=128

typedef unsigned short u16;
typedef __attribute__((ext_vector_type(8))) short s8v;   // 8 x bf16 (4 VGPR)
typedef __attribute__((ext_vector_type(4))) short s4v;   // 4 x bf16 (8B)
typedef __attribute__((ext_vector_type(4))) float f4v;   // MFMA accumulator

__device__ __forceinline__ u16 f2b(float f) {
  unsigned u = __builtin_bit_cast(unsigned, f);
  unsigned r = u + 0x7FFFu + ((u >> 16) & 1u);   // RNE
  return (u16)(r >> 16);
}
__device__ __forceinline__ float b2f(u16 h) {
  unsigned u = ((unsigned)h) << 16;
  return __builtin_bit_cast(float, u);
}

// async global->LDS, 16B per lane; LDS dest is wave-uniform base + lane*16
__device__ __forceinline__ void cp16(const void* g, void* l) {
  __builtin_amdgcn_global_load_lds(
      (const __attribute__((address_space(1))) unsigned int*)g,
      (__attribute__((address_space(3))) unsigned int*)l, 16, 0, 0);
}

// ---- shared MFMA core: C[128x128] += A[128xK] * BT[128xK]^T, bf16, BK=32 ----
// LDS tile logical [128 rows][32 cols]; element (R, quarter Q) stored at
// physical quarter Q ^ ((R>>1)&3). Stage keeps LDS dest linear; global SOURCE
// is quarter-permuted (rule #21 both-sides). 2-slot double buffer,
// counted vmcnt(4) so next tile's loads stay in flight across barriers.
__device__ __forceinline__ void stage_tile(const u16* g, int ld, u16* lds,
                                           int wv, int ln) {
  const int q = (ln & 3) ^ ((ln >> 3) & 3);
#pragma unroll
  for (int i = 0; i < 2; ++i) {
    const int c = wv * 2 + i;                       // 1KB chunk id 0..7
    const u16* src = g + (size_t)(c * 16 + (ln >> 2)) * ld + q * 8;
    cp16(src, lds + c * 512);
  }
}

__device__ __forceinline__ void gemm_core(
    const u16* __restrict__ A, int lda, const u16* __restrict__ BT, int ldb,
    int K, u16* As, u16* Bs, f4v acc[4][4])
{
  const int tid = threadIdx.x;
  const int ln = tid & 63, wv = tid >> 6;
  const int arow = (wv >> 1) * 64 + (ln & 15);
  const int brow = (wv & 1) * 64 + (ln & 15);
  const int koff = (((ln >> 4) ^ ((ln >> 1) & 3)) * 8);
  const int nt = K >> 5;
  stage_tile(A, lda, As, wv, ln);
  stage_tile(BT, ldb, Bs, wv, ln);
  stage_tile(A + 32, lda, As + 4096, wv, ln);
  stage_tile(BT + 32, ldb, Bs + 4096, wv, ln);
  int slot = 0;
  for (int t = 0; t < nt; ++t) {
    if (t + 1 < nt) asm volatile("s_waitcnt vmcnt(4)" ::: "memory");
    else            asm volatile("s_waitcnt vmcnt(0)" ::: "memory");
    __builtin_amdgcn_s_barrier();
    __builtin_amdgcn_sched_barrier(0);
    const u16* Ab = As + slot * 4096;
    const u16* Bb = Bs + slot * 4096;
    s8v af[4], bf[4];
#pragma unroll
    for (int f = 0; f < 4; ++f)
      af[f] = *(const s8v*)(Ab + (arow + f * 16) * 32 + koff);
#pragma unroll
    for (int f = 0; f < 4; ++f)
      bf[f] = *(const s8v*)(Bb + (brow + f * 16) * 32 + koff);
#pragma unroll
    for (int mf = 0; mf < 4; ++mf)
#pragma unroll
      for (int nf = 0; nf < 4; ++nf)
        acc[mf][nf] = __builtin_amdgcn_mfma_f32_16x16x32_bf16(
            af[mf], bf[nf], acc[mf][nf], 0, 0, 0);
    __builtin_amdgcn_sched_barrier(0);
    __builtin_amdgcn_s_barrier();
    if (t + 2 < nt) {
      stage_tile(A + (t + 2) * 32, lda, As + slot * 4096, wv, ln);
      stage_tile(BT + (t + 2) * 32, ldb, Bs + slot * 4096, wv, ln);
    }
    slot ^= 1;
  }
}

// ---- epilogue: fragments -> LDS (bf16, row stride 72 = 16B aligned) --------
__device__ __forceinline__ void frag_to_lds(u16* S, const f4v acc[4][4],
                                            int ln, int wv) {
  u16* q = S + wv * 4608;
#pragma unroll
  for (int mf = 0; mf < 4; ++mf)
#pragma unroll
    for (int nf = 0; nf < 4; ++nf)
#pragma unroll
      for (int r = 0; r < 4; ++r)
        q[(mf * 16 + ((ln >> 4) << 2) + r) * 72 + nf * 16 + (ln & 15)] =
            f2b(acc[mf][nf][r]);
}

// Transposed: T(c,r) at quad((c>>6)<<1 | r>>6)*4608 + (c&63)*72 + (r&63).
__device__ __forceinline__ void frag_to_lds_T(u16* S, const f4v acc[4][4],
                                              int ln, int wv) {
  const int wr = wv >> 1, wc = wv & 1;
  u16* q = S + ((wc << 1) + wr) * 4608;
#pragma unroll
  for (int mf = 0; mf < 4; ++mf)
#pragma unroll
    for (int nf = 0; nf < 4; ++nf) {
      const int cl = nf * 16 + (ln & 15);
      const int rl = mf * 16 + ((ln >> 4) << 2);
      s4v o4;
#pragma unroll
      for (int r = 0; r < 4; ++r) o4[r] = (short)f2b(acc[mf][nf][r]);
      *(s4v*)(q + cl * 72 + rl) = o4;
    }
}

template <typename F>
__device__ __forceinline__ void epi_loop(u16* S, const f4v acc[4][4], F f) {
  const int tid = threadIdx.x;
  frag_to_lds(S, acc, tid & 63, tid >> 6);
  __syncthreads();
#pragma unroll
  for (int p = 0; p < 8; ++p) {
    const int r = p * 16 + (tid >> 4);
    const int c0 = (tid & 15) * 8;
    const int quad = ((r >> 6) << 1) + (c0 >> 6);
    s8v vv = *(const s8v*)(S + quad * 4608 + (r & 63) * 72 + (c0 & 63));
    f(r, c0, vv);
  }
}

// transposed variant: r is the ORIGINAL COLUMN, c0 the ORIGINAL ROW base.
template <typename F>
__device__ __forceinline__ void epi_loop_T(u16* S, const f4v acc[4][4], F f) {
  const int tid = threadIdx.x;
  frag_to_lds_T(S, acc, tid & 63, tid >> 6);
  __syncthreads();
#pragma unroll
  for (int p = 0; p < 8; ++p) {
    const int r = p * 16 + (tid >> 4);        // column index 0..127
    const int c0 = (tid & 15) * 8;            // row base 0..120
    const int quad = ((r >> 6) << 1) + (c0 >> 6);
    s8v vv = *(const s8v*)(S + quad * 4608 + (r & 63) * 72 + (c0 & 63));
    f(r, c0, vv);
  }
}

// -------- fused bf16 cast of x + all 5 weight transposes --------------------
__global__ __launch_bounds__(256) void castw_all(
    const float* __restrict__ x, const float* __restrict__ Wq,
    const float* __restrict__ Wk, const float* __restrict__ Wv,
    const float* __restrict__ Wg, const float* __restrict__ Wo,
    u16* __restrict__ xb, u16* __restrict__ WTa, u16* __restrict__ WoT)
{
  __shared__ float t[32][33];
  const int id = blockIdx.x;
  if (id < 4096) {                      // cast x -> xb (float4 per thread)
    const int i = id * 256 + threadIdx.x;
    const float4 v = ((const float4*)x)[i];
    u16* p = xb + i * 4;
    p[0] = f2b(v.x); p[1] = f2b(v.y); p[2] = f2b(v.z); p[3] = f2b(v.w);
    return;
  }
  const int wid = id - 4096;
  const float* src; u16* dst; int R, C, local;
  if (wid < 1024)      { src = Wq; dst = WTa;           R = 1024; C = 1024; local = wid; }
  else if (wid < 2048) { src = Wk; dst = WTa + 1048576; R = 1024; C = 1024; local = wid - 1024; }
  else if (wid < 4096) { src = Wv; dst = WTa + 2097152; R = 1024; C = 2048; local = wid - 2048; }
  else if (wid < 6144) { src = Wg; dst = WTa + 4194304; R = 1024; C = 2048; local = wid - 4096; }
  else                 { src = Wo; dst = WoT;           R = 2048; C = 1024; local = wid - 6144; }
  const int nx = C >> 5;
  const int c0 = (local % nx) * 32, r0 = (local / nx) * 32;
  const int lx = threadIdx.x & 31, ly = threadIdx.x >> 5;
#pragma unroll
  for (int i = 0; i < 32; i += 8)
    t[ly + i][lx] = src[(size_t)(r0 + ly + i) * C + c0 + lx];
  __syncthreads();
#pragma unroll
  for (int i = 0; i < 32; i += 8)
    dst[(size_t)(c0 + ly + i) * R + r0 + lx] = f2b(t[lx][ly + i]);
}

// kt [bh][2048][256] -> ktT [bh][256][2048]
__global__ __launch_bounds__(256) void trans_kt(
    const u16* __restrict__ kt, u16* __restrict__ ktT)
{
  __shared__ u16 t[32][33];
  const int id = blockIdx.x;                  // 4096
  const int z = id >> 9, local = id & 511;
  const int c0 = (local & 7) * 32, r0 = (local >> 3) * 32;
  const size_t boff = (size_t)z * 2048 * 256;
  const int lx = threadIdx.x & 31, ly = threadIdx.x >> 5;
#pragma unroll
  for (int i = 0; i < 32; i += 8)
    t[ly + i][lx] = kt[boff + (size_t)(r0 + ly + i) * 256 + c0 + lx];
  __syncthreads();
#pragma unroll
  for (int i = 0; i < 32; i += 8)
    ktT[boff + (size_t)(c0 + ly + i) * 2048 + r0 + lx] = t[lx][ly + i];
}

// ---------------- low-rank gate part 1: tmp[4096,16] = x @ w1 ----------------
__global__ __launch_bounds__(256) void lowrank1(
    const float* __restrict__ x, const float* __restrict__ w1,
    float* __restrict__ tmp)
{
  const int idx = blockIdx.x * 256 + threadIdx.x;
  const int m = idx >> 4, i = idx & 15;
  const float* xr = x + (size_t)m * 1024;
  float acc = 0.f;
#pragma unroll 4
  for (int kk = 0; kk < 1024; kk += 4) {
    const float4 xv = *(const float4*)(xr + kk);
    acc = fmaf(xv.x, w1[(kk + 0) * 16 + i], acc);
    acc = fmaf(xv.y, w1[(kk + 1) * 16 + i], acc);
    acc = fmaf(xv.z, w1[(kk + 2) * 16 + i], acc);
    acc = fmaf(xv.w, w1[(kk + 3) * 16 + i], acc);
  }
  tmp[idx] = acc;
}

// -------- gate cumsum -> bf16 decay factors dq = e^B, dk = e^-B; Dc = e^B_end
__global__ __launch_bounds__(256) void gate_cum(
    const float* __restrict__ tmp, const float* __restrict__ w2,
    const float* __restrict__ bias, u16* __restrict__ dq, u16* __restrict__ dk,
    float* __restrict__ Dc)
{
  __shared__ float ls_t[2048];   // tmp slice for this (b, c): 128 t x 16
  const int b = blockIdx.y >> 4, c = blockIdx.y & 15;
  const int h = blockIdx.x;
  const int i = threadIdx.x;
  const int n = h * 256 + i;
  const int bh = b * 4 + h;
  const float* tp = tmp + ((size_t)(b * 2048 + c * 128)) * 16;
#pragma unroll
  for (int r = 0; r < 8; ++r) ls_t[r * 256 + threadIdx.x] = tp[r * 256 + threadIdx.x];
  __syncthreads();
  float w2c[16];
#pragma unroll
  for (int r = 0; r < 16; ++r) w2c[r] = w2[r * 1024 + n];
  const float bn = bias[n];
  const size_t base = ((size_t)bh * 2048 + c * 128) * 256 + i;
  float B = 0.f;
  for (int t = 0; t < 128; ++t) {
    float gl = bn;
    const float* tr = ls_t + t * 16;
#pragma unroll
    for (int r = 0; r < 16; ++r) gl = fmaf(tr[r], w2c[r], gl);
    const float ls = fminf(gl, 0.f) - log1pf(expf(-fabsf(gl)));
    B += ls * 0.0625f;
    const float eB = expf(B);
    dq[base + (size_t)t * 256] = f2b(eB);
    dk[base + (size_t)t * 256] = f2b(1.f / eB);
  }
  Dc[(bh * 16 + c) * 256 + i] = expf(B);
}

// ---------------- fused projections: xb[4096,1024] @ [Wq|Wk|Wv|Wg] ----------
// q/k: decay fused, row-major. v: written TRANSPOSED directly to vT[bh][j][t].
__global__ __launch_bounds__(256) void proj_all(
    const u16* __restrict__ xb, const u16* __restrict__ WT,
    const u16* __restrict__ dq, const u16* __restrict__ dk,
    u16* __restrict__ qt, u16* __restrict__ kt,
    u16* __restrict__ vT, u16* __restrict__ gpre)
{
  __shared__ __align__(16) u16 S[18432];
  u16* As = S; u16* Bs = S + 8192;
  // XCD-chunked swizzle, n-fast within XCD
  const int id = blockIdx.x;
  const int xcd = id & 7, jb = id >> 3;
  const int m0 = (jb / 6) * 128;
  const int n0 = (xcd * 6 + (jb % 6)) * 128;
  f4v acc[4][4];
#pragma unroll
  for (int zi = 0; zi < 4; ++zi)
#pragma unroll
    for (int zj = 0; zj < 4; ++zj) acc[zi][zj] = (f4v){0.f, 0.f, 0.f, 0.f};
  gemm_core(xb + (size_t)m0 * 1024, 1024, WT + (size_t)n0 * 1024, 1024, 1024,
            As, Bs, acc);
  const int bb = m0 >> 11;              // batch (tile is within one b)
  const int t0 = m0 & 2047;
  if (n0 < 1024) {
    epi_loop(S, acc, [&](int r, int c0, s8v vv) {
      const int t = t0 + r;
      const int n = n0 + c0;
      const int bh = bb * 4 + (n >> 8);
      const size_t off = ((size_t)bh * 2048 + t) * 256 + (n & 255);
      const s8v dv = *(const s8v*)(dq + off);
      s8v o8;
#pragma unroll
      for (int e = 0; e < 8; ++e)
        o8[e] = (short)f2b(b2f((u16)vv[e]) * 0.0625f * b2f((u16)dv[e]));
      *(s8v*)(qt + off) = o8;
    });
  } else if (n0 < 2048) {
    epi_loop(S, acc, [&](int r, int c0, s8v vv) {
      const int t = t0 + r;
      const int nn = n0 + c0 - 1024;
      const int bh = bb * 4 + (nn >> 8);
      const size_t off = ((size_t)bh * 2048 + t) * 256 + (nn & 255);
      const s8v dv = *(const s8v*)(dk + off);
      s8v o8;
#pragma unroll
      for (int e = 0; e < 8; ++e)
        o8[e] = (short)f2b(b2f((u16)vv[e]) * b2f((u16)dv[e]));
      *(s8v*)(kt + off) = o8;
    });
  } else if (n0 < 4096) {
    const int nn0 = n0 - 2048;
    const int bh = bb * 4 + (nn0 >> 9);
    const int jj0 = nn0 & 511;
    epi_loop_T(S, acc, [&](int r, int c0, s8v vv) {
      // r = column offset (j), c0 = row base (t)
      *(s8v*)(vT + ((size_t)(bh * 512 + jj0 + r)) * 2048 + t0 + c0) = vv;
    });
  } else {
    epi_loop(S, acc, [&](int r, int c0, s8v vv) {
      *(s8v*)(gpre + (size_t)(m0 + r) * 2048 + (n0 + c0 - 4096)) = vv;
    });
  }
}

// ------- merged scan GEMMs: x<8 -> chunk_state tile, x==8 -> qk_causal ------
__global__ __launch_bounds__(256) void scan_gemms(
    const u16* __restrict__ vT, const u16* __restrict__ ktT,
    const u16* __restrict__ qt, const u16* __restrict__ kt,
    u16* __restrict__ UT, u16* __restrict__ Aw)
{
  __shared__ __align__(16) u16 S[18432];
  u16* As = S; u16* Bs = S + 8192;
  const int bhc = blockIdx.y, bh = bhc >> 4, c = bhc & 15;
  f4v acc[4][4];
#pragma unroll
  for (int zi = 0; zi < 4; ++zi)
#pragma unroll
    for (int zj = 0; zj < 4; ++zj) acc[zi][zj] = (f4v){0.f, 0.f, 0.f, 0.f};
  if (blockIdx.x < 8) {
    const int mt = blockIdx.x >> 1, nt = blockIdx.x & 1;
    gemm_core(vT + ((size_t)bh * 512 + mt * 128) * 2048 + c * 128, 2048,
              ktT + ((size_t)bh * 256 + nt * 128) * 2048 + c * 128, 2048, 128,
              As, Bs, acc);
    epi_loop(S, acc, [&](int r, int c0, s8v vv) {
      const int j = mt * 128 + r;
      const int i = nt * 128 + c0;
      *(s8v*)(UT + (((size_t)(bh * 512 + j)) * 16 + c) * 256 + i) = vv;
    });
  } else {
    const size_t base = ((size_t)bh * 2048 + c * 128) * 256;
    gemm_core(qt + base, 256, kt + base, 256, 256, As, Bs, acc);
    u16* Ap = Aw + (size_t)bhc * 16384;
    epi_loop(S, acc, [&](int r, int c0, s8v vv) {
      s8v o8;
#pragma unroll
      for (int e = 0; e < 8; ++e)
        o8[e] = (c0 + e <= r) ? vv[e] : (short)0;
      *(s8v*)(Ap + r * 128 + c0) = o8;
    });
  }
}

// ------ serial inter-chunk scan, in place on UT (bf16, fp32 accum) ----------
// c-loop unrolled: the 16 reads are address-independent of the carried S,
// so the compiler can issue them ahead of the serial multiply chain.
__global__ __launch_bounds__(256) void state_scan(
    u16* __restrict__ UT, const float* __restrict__ Dc)
{
  const int blk = blockIdx.x;               // 4096 = bh*512 + j
  const int bh = blk >> 9, j = blk & 511;
  const int i = threadIdx.x;
  u16* Up = UT + ((size_t)(bh * 512 + j)) * 16 * 256 + i;
  const float* Dp = Dc + bh * 16 * 256 + i;
  float Sa = 0.f;
#pragma unroll
  for (int c = 0; c < 16; ++c) {
    const float u = b2f(Up[c * 256]);
    const float d = Dp[c * 256];
    Up[c * 256] = f2b(Sa);
    Sa = d * (Sa + u);
  }
}

// -------- ob = Aw @ V + qt @ S  (per bhc, 128-col tile of HV) ---------------
__global__ __launch_bounds__(256) void intra_k(
    const u16* __restrict__ Aw, const u16* __restrict__ qt,
    const u16* __restrict__ vT, const u16* __restrict__ UT, u16* __restrict__ ob)
{
  __shared__ __align__(16) u16 S[18432];
  u16* As = S; u16* Bs = S + 8192;
  const int jt = blockIdx.x;
  const int bhc = blockIdx.y, bh = bhc >> 4, c = bhc & 15;
  f4v acc[4][4];
#pragma unroll
  for (int zi = 0; zi < 4; ++zi)
#pragma unroll
    for (int zj = 0; zj < 4; ++zj) acc[zi][zj] = (f4v){0.f, 0.f, 0.f, 0.f};
  gemm_core(Aw + (size_t)bhc * 16384, 128,
            vT + ((size_t)bh * 512 + jt * 128) * 2048 + c * 128, 2048, 128,
            As, Bs, acc);
  gemm_core(qt + ((size_t)bh * 2048 + c * 128) * 256, 256,
            UT + ((size_t)(bh * 512 + jt * 128)) * 4096 + (size_t)c * 256, 4096, 256,
            As, Bs, acc);
  const int b = bh >> 2, h = bh & 3;
  epi_loop(S, acc, [&](int r, int c0, s8v vv) {
    const int t = c * 128 + r;
    const int j = jt * 128 + c0;
    *(s8v*)(ob + ((size_t)(b * 2048 + t)) * 2048 + h * 512 + j) = vv;
  });
}

// ------- group RMSNorm (512) + SiLU gate, in place on ob (vectorized) -------
__global__ __launch_bounds__(256) void rms_silu(
    u16* __restrict__ o, const u16* __restrict__ gpre, const float* __restrict__ w)
{
  const int grp = blockIdx.x * 4 + (threadIdx.x >> 6);  // 16384 groups (b,t,h)
  const int lane = threadIdx.x & 63;
  const size_t base = (size_t)(grp >> 2) * 2048 + (grp & 3) * 512 + lane * 8;
  const s8v xv = *(const s8v*)(o + base);
  float xf[8];
  float ss = 0.f;
#pragma unroll
  for (int i = 0; i < 8; ++i) {
    xf[i] = b2f((u16)xv[i]);
    ss = fmaf(xf[i], xf[i], ss);
  }
#pragma unroll
  for (int off = 1; off < 64; off <<= 1) ss += __shfl_xor(ss, off, 64);
  const float r = rsqrtf(ss * (1.f / 512.f) + 1e-5f);
  const s8v gv = *(const s8v*)(gpre + base);
  const float4 w0 = *(const float4*)(w + lane * 8);
  const float4 w1 = *(const float4*)(w + lane * 8 + 4);
  const float wf[8] = {w0.x, w0.y, w0.z, w0.w, w1.x, w1.y, w1.z, w1.w};
  s8v o8;
#pragma unroll
  for (int i = 0; i < 8; ++i) {
    const float gp = b2f((u16)gv[i]);
    const float sig = 1.f / (1.f + expf(-gp));
    o8[i] = (short)f2b(xf[i] * r * wf[i] * gp * sig);
  }
  *(s8v*)(o + base) = o8;
}

// ---------------- final: out = ob @ Wo, split-K=2 into pout -----------------
__global__ __launch_bounds__(256) void gemm_out(
    const u16* __restrict__ ob, const u16* __restrict__ WoT,
    float* __restrict__ pout)
{
  __shared__ __align__(16) u16 S[18432];
  u16* As = S; u16* Bs = S + 8192;
  const int id = blockIdx.x;                 // 512 blocks, 64 per XCD
  const int wg = (id & 7) * 64 + (id >> 3);
  const int ks = wg >> 8;                    // K-half
  const int tt = wg & 255;
  const int m0 = (tt & 31) * 128, n0 = (tt >> 5) * 128;
  f4v acc[4][4];
#pragma unroll
  for (int zi = 0; zi < 4; ++zi)
#pragma unroll
    for (int zj = 0; zj < 4; ++zj) acc[zi][zj] = (f4v){0.f, 0.f, 0.f, 0.f};
  gemm_core(ob + (size_t)m0 * 2048 + ks * 1024, 2048,
            WoT + (size_t)n0 * 2048 + ks * 1024, 2048, 1024, As, Bs, acc);
  const int tid = threadIdx.x;
  const int ln = tid & 63, wv = tid >> 6;
  const int wr = wv >> 1, wc = wv & 1;
  float* po = pout + (size_t)ks * 4194304;
#pragma unroll
  for (int mf = 0; mf < 4; ++mf)
#pragma unroll
    for (int nf = 0; nf < 4; ++nf)
#pragma unroll
      for (int r = 0; r < 4; ++r) {
        const int m = m0 + wr * 64 + mf * 16 + ((ln >> 4) << 2) + r;
        const int n = n0 + wc * 64 + nf * 16 + (ln & 15);
        po[(size_t)m * 1024 + n] = acc[mf][nf][r];
      }
}

__global__ __launch_bounds__(256) void reduce_out(
    const float* __restrict__ p, float* __restrict__ out)
{
  const int i = blockIdx.x * 256 + threadIdx.x;   // float4 granularity
  const float4 a = ((const float4*)p)[i];
  const float4 b = ((const float4*)(p + 4194304))[i];
  ((float4*)out)[i] = make_float4(a.x + b.x, a.y + b.y, a.z + b.z, a.w + b.w);
}

extern "C" void kernel_launch(void* const* d_in, const int* in_sizes, int n_in,
                              void* d_out, int out_size, void* d_ws, size_t ws_size,
                              hipStream_t stream) {
  const float* x    = (const float*)d_in[0];
  const float* Wq   = (const float*)d_in[1];
  const float* Wk   = (const float*)d_in[2];
  const float* Wv   = (const float*)d_in[3];
  const float* Wg   = (const float*)d_in[4];
  const float* w1   = (const float*)d_in[5];
  const float* w2   = (const float*)d_in[6];
  const float* gb   = (const float*)d_in[7];
  const float* Wo   = (const float*)d_in[8];
  const float* rmsw = (const float*)d_in[9];
  float* out = (float*)d_out;

  char* W = (char*)d_ws;
  u16*   xb   = (u16*)W;   W += (size_t)8  << 20;   // [4096][1024]
  u16*   WTa  = (u16*)W;   W += (size_t)12 << 20;   // [6144][1024]
  u16*   WoT  = (u16*)W;   W += (size_t)4  << 20;   // [1024][2048]
  u16*   qt   = (u16*)W;   W += (size_t)8  << 20;   // [8][2048][256]
  u16*   kt   = (u16*)W;   W += (size_t)8  << 20;
  u16*   vT   = (u16*)W;   W += (size_t)16 << 20;   // [8][512][2048]
  u16*   ktT  = (u16*)W;   W += (size_t)8  << 20;   // [8][256][2048]
  u16*   gpre = (u16*)W;   W += (size_t)16 << 20;   // [4096][2048]
  float* tmp  = (float*)W; W += (size_t)256 << 10;  // [4096][16]
  float* Dc   = (float*)W; W += (size_t)128 << 10;  // [8][16][256]
  u16*   dq   = (u16*)W;   W += (size_t)8  << 20;   // [8][2048][256] bf16 e^B
  u16*   dk   = (u16*)W;   W += (size_t)8  << 20;   // e^-B
  u16*   UT   = (u16*)W;   W += (size_t)32 << 20;   // [8][512][16][256]
  u16*   Aw   = (u16*)W;   W += (size_t)4  << 20;   // [128][128][128]
  u16*   ob   = (u16*)W;   W += (size_t)16 << 20;   // [4096][2048]
  float* pout = (float*)W; W += (size_t)32 << 20;   // [2][4096][1024]

  // gate pipeline first (dq/dk needed by proj_all)
  hipLaunchKernelGGL(lowrank1, dim3(256), dim3(256), 0, stream, x, w1, tmp);
  hipLaunchKernelGGL(gate_cum, dim3(4, 32), dim3(256), 0, stream,
                     tmp, w2, gb, dq, dk, Dc);

  // bf16 cast of x + all weight transposes, one kernel
  hipLaunchKernelGGL(castw_all, dim3(12288), dim3(256), 0, stream,
                     x, Wq, Wk, Wv, Wg, Wo, xb, WTa, WoT);

  // fused q/k/v/g projections; v emitted transposed, decay fused
  hipLaunchKernelGGL(proj_all, dim3(1536), dim3(256), 0, stream,
                     xb, WTa, dq, dk, qt, kt, vT, gpre);

  // kt -> ktT (only remaining layout pass)
  hipLaunchKernelGGL(trans_kt, dim3(4096), dim3(256), 0, stream, kt, ktT);

  // chunked scan: (chunk_state || qk_causal) -> state_scan -> intra
  hipLaunchKernelGGL(scan_gemms, dim3(9, 128), dim3(256), 0, stream,
                     vT, ktT, qt, kt, UT, Aw);
  hipLaunchKernelGGL(state_scan, dim3(4096), dim3(256), 0, stream, UT, Dc);
  hipLaunchKernelGGL(intra_k, dim3(4, 128), dim3(256), 0, stream, Aw, qt, vT, UT, ob);

  // group RMSNorm + SiLU gate (in place), then output projection (split-K)
  hipLaunchKernelGGL(rms_silu, dim3(4096), dim3(256), 0, stream, ob, gpre, rmsw);
  hipLaunchKernelGGL(gemm_out, dim3(512), dim3(256), 0, stream, ob, WoT, pout);
  hipLaunchKernelGGL(reduce_out, dim3(4096), dim3(256), 0, stream, pout, out);
}

// Round 17
// 257.211 us; speedup vs baseline: 1.0440x; 1.0213x over previous
//
#include <hip/hip_runtime.h>
#include <cstdint>
#include <cstddef>

// GLA forward, bf16 MFMA pipeline. r17: gemm_core uses 3 LDS slots with
// stage-2-ahead issued right after the (single) per-K-step barrier -> one
// barrier per K-step instead of two (+1 trailing per call). Counted vmcnt(4).
// Everything else = round-14 best config (259.8us).
// B=2, T=2048, D=1024, H=4, HK=256, HV=512, DK=1024, DV=2048, LR=16, CHUNK=128

typedef unsigned short u16;
typedef __attribute__((ext_vector_type(8))) short s8v;   // 8 x bf16 (4 VGPR)
typedef __attribute__((ext_vector_type(4))) short s4v;   // 4 x bf16 (8B)
typedef __attribute__((ext_vector_type(4))) float f4v;   // MFMA accumulator

__device__ __forceinline__ u16 f2b(float f) {
  unsigned u = __builtin_bit_cast(unsigned, f);
  unsigned r = u + 0x7FFFu + ((u >> 16) & 1u);   // RNE
  return (u16)(r >> 16);
}
__device__ __forceinline__ float b2f(u16 h) {
  unsigned u = ((unsigned)h) << 16;
  return __builtin_bit_cast(float, u);
}

// async global->LDS, 16B per lane; LDS dest is wave-uniform base + lane*16
__device__ __forceinline__ void cp16(const void* g, void* l) {
  __builtin_amdgcn_global_load_lds(
      (const __attribute__((address_space(1))) unsigned int*)g,
      (__attribute__((address_space(3))) unsigned int*)l, 16, 0, 0);
}

// ---- shared MFMA core: C[128x128] += A[128xK] * BT[128xK]^T, bf16, BK=32 ----
// LDS tile logical [128 rows][32 cols]; element (R, quarter Q) stored at
// physical quarter Q ^ ((R>>1)&3). Stage keeps LDS dest linear; global SOURCE
// is quarter-permuted (rule #21 both-sides).
// 3-slot rotation, ONE barrier per K-step:
//   vmcnt(4) -> barrier B_t -> stage(t+2 -> slot (t+2)%3) -> read slot t%3+MFMA
// Safety: at B_t all waves completed step t-1's body (ds_read completion is
// forced before MFMA issue), so slot (t+2)%3 (last read at t-1) is free.
// Trailing barrier protects LDS reuse (epilogue / second core call).
__device__ __forceinline__ void stage_tile(const u16* g, int ld, u16* lds,
                                           int wv, int ln) {
  const int q = (ln & 3) ^ ((ln >> 3) & 3);
#pragma unroll
  for (int i = 0; i < 2; ++i) {
    const int c = wv * 2 + i;                       // 1KB chunk id 0..7
    const u16* src = g + (size_t)(c * 16 + (ln >> 2)) * ld + q * 8;
    cp16(src, lds + c * 512);
  }
}

__device__ __forceinline__ void gemm_core(
    const u16* __restrict__ A, int lda, const u16* __restrict__ BT, int ldb,
    int K, u16* As, u16* Bs, f4v acc[4][4])
{
  const int tid = threadIdx.x;
  const int ln = tid & 63, wv = tid >> 6;
  const int arow = (wv >> 1) * 64 + (ln & 15);
  const int brow = (wv & 1) * 64 + (ln & 15);
  const int koff = (((ln >> 4) ^ ((ln >> 1) & 3)) * 8);
  const int nt = K >> 5;
  // prologue: stage tiles 0,1 into slots 0,1 (8 loads/thread in flight)
  stage_tile(A, lda, As, wv, ln);
  stage_tile(BT, ldb, Bs, wv, ln);
  stage_tile(A + 32, lda, As + 4096, wv, ln);
  stage_tile(BT + 32, ldb, Bs + 4096, wv, ln);
  int slot = 0;
  for (int t = 0; t < nt; ++t) {
    if (t + 1 < nt) asm volatile("s_waitcnt vmcnt(4)" ::: "memory");
    else            asm volatile("s_waitcnt vmcnt(0)" ::: "memory");
    __builtin_amdgcn_s_barrier();          // tile t visible; slot (t+2)%3 free
    __builtin_amdgcn_sched_barrier(0);
    if (t + 2 < nt) {                      // issue tile t+2 loads EARLY
      const int s2 = (slot >= 1) ? slot - 1 : 2;   // (slot+2)%3
      stage_tile(A + (t + 2) * 32, lda, As + s2 * 4096, wv, ln);
      stage_tile(BT + (t + 2) * 32, ldb, Bs + s2 * 4096, wv, ln);
    }
    const u16* Ab = As + slot * 4096;
    const u16* Bb = Bs + slot * 4096;
    s8v af[4], bf[4];
#pragma unroll
    for (int f = 0; f < 4; ++f)
      af[f] = *(const s8v*)(Ab + (arow + f * 16) * 32 + koff);
#pragma unroll
    for (int f = 0; f < 4; ++f)
      bf[f] = *(const s8v*)(Bb + (brow + f * 16) * 32 + koff);
#pragma unroll
    for (int mf = 0; mf < 4; ++mf)
#pragma unroll
      for (int nf = 0; nf < 4; ++nf)
        acc[mf][nf] = __builtin_amdgcn_mfma_f32_16x16x32_bf16(
            af[mf], bf[nf], acc[mf][nf], 0, 0, 0);
    __builtin_amdgcn_sched_barrier(0);
    slot = (slot == 2) ? 0 : slot + 1;
  }
  __builtin_amdgcn_s_barrier();            // all reads done before LDS reuse
}

// ---- epilogue: fragments -> LDS (bf16, row stride 72 = 16B aligned) --------
__device__ __forceinline__ void frag_to_lds(u16* S, const f4v acc[4][4],
                                            int ln, int wv) {
  u16* q = S + wv * 4608;
#pragma unroll
  for (int mf = 0; mf < 4; ++mf)
#pragma unroll
    for (int nf = 0; nf < 4; ++nf)
#pragma unroll
      for (int r = 0; r < 4; ++r)
        q[(mf * 16 + ((ln >> 4) << 2) + r) * 72 + nf * 16 + (ln & 15)] =
            f2b(acc[mf][nf][r]);
}

// Transposed: T(c,r) at quad((c>>6)<<1 | r>>6)*4608 + (c&63)*72 + (r&63).
__device__ __forceinline__ void frag_to_lds_T(u16* S, const f4v acc[4][4],
                                              int ln, int wv) {
  const int wr = wv >> 1, wc = wv & 1;
  u16* q = S + ((wc << 1) + wr) * 4608;
#pragma unroll
  for (int mf = 0; mf < 4; ++mf)
#pragma unroll
    for (int nf = 0; nf < 4; ++nf) {
      const int cl = nf * 16 + (ln & 15);
      const int rl = mf * 16 + ((ln >> 4) << 2);
      s4v o4;
#pragma unroll
      for (int r = 0; r < 4; ++r) o4[r] = (short)f2b(acc[mf][nf][r]);
      *(s4v*)(q + cl * 72 + rl) = o4;
    }
}

template <typename F>
__device__ __forceinline__ void epi_loop(u16* S, const f4v acc[4][4], F f) {
  const int tid = threadIdx.x;
  frag_to_lds(S, acc, tid & 63, tid >> 6);
  __syncthreads();
#pragma unroll
  for (int p = 0; p < 8; ++p) {
    const int r = p * 16 + (tid >> 4);
    const int c0 = (tid & 15) * 8;
    const int quad = ((r >> 6) << 1) + (c0 >> 6);
    s8v vv = *(const s8v*)(S + quad * 4608 + (r & 63) * 72 + (c0 & 63));
    f(r, c0, vv);
  }
}

// transposed variant: r is the ORIGINAL COLUMN, c0 the ORIGINAL ROW base.
template <typename F>
__device__ __forceinline__ void epi_loop_T(u16* S, const f4v acc[4][4], F f) {
  const int tid = threadIdx.x;
  frag_to_lds_T(S, acc, tid & 63, tid >> 6);
  __syncthreads();
#pragma unroll
  for (int p = 0; p < 8; ++p) {
    const int r = p * 16 + (tid >> 4);        // column index 0..127
    const int c0 = (tid & 15) * 8;            // row base 0..120
    const int quad = ((r >> 6) << 1) + (c0 >> 6);
    s8v vv = *(const s8v*)(S + quad * 4608 + (r & 63) * 72 + (c0 & 63));
    f(r, c0, vv);
  }
}

// -------- fused bf16 cast of x + all 5 weight transposes --------------------
__global__ __launch_bounds__(256) void castw_all(
    const float* __restrict__ x, const float* __restrict__ Wq,
    const float* __restrict__ Wk, const float* __restrict__ Wv,
    const float* __restrict__ Wg, const float* __restrict__ Wo,
    u16* __restrict__ xb, u16* __restrict__ WTa, u16* __restrict__ WoT)
{
  __shared__ float t[32][33];
  const int id = blockIdx.x;
  if (id < 4096) {                      // cast x -> xb (float4 per thread)
    const int i = id * 256 + threadIdx.x;
    const float4 v = ((const float4*)x)[i];
    u16* p = xb + i * 4;
    p[0] = f2b(v.x); p[1] = f2b(v.y); p[2] = f2b(v.z); p[3] = f2b(v.w);
    return;
  }
  const int wid = id - 4096;
  const float* src; u16* dst; int R, C, local;
  if (wid < 1024)      { src = Wq; dst = WTa;           R = 1024; C = 1024; local = wid; }
  else if (wid < 2048) { src = Wk; dst = WTa + 1048576; R = 1024; C = 1024; local = wid - 1024; }
  else if (wid < 4096) { src = Wv; dst = WTa + 2097152; R = 1024; C = 2048; local = wid - 2048; }
  else if (wid < 6144) { src = Wg; dst = WTa + 4194304; R = 1024; C = 2048; local = wid - 4096; }
  else                 { src = Wo; dst = WoT;           R = 2048; C = 1024; local = wid - 6144; }
  const int nx = C >> 5;
  const int c0 = (local % nx) * 32, r0 = (local / nx) * 32;
  const int lx = threadIdx.x & 31, ly = threadIdx.x >> 5;
#pragma unroll
  for (int i = 0; i < 32; i += 8)
    t[ly + i][lx] = src[(size_t)(r0 + ly + i) * C + c0 + lx];
  __syncthreads();
#pragma unroll
  for (int i = 0; i < 32; i += 8)
    dst[(size_t)(c0 + ly + i) * R + r0 + lx] = f2b(t[lx][ly + i]);
}

// kt [bh][2048][256] -> ktT [bh][256][2048]
__global__ __launch_bounds__(256) void trans_kt(
    const u16* __restrict__ kt, u16* __restrict__ ktT)
{
  __shared__ u16 t[32][33];
  const int id = blockIdx.x;                  // 4096
  const int z = id >> 9, local = id & 511;
  const int c0 = (local & 7) * 32, r0 = (local >> 3) * 32;
  const size_t boff = (size_t)z * 2048 * 256;
  const int lx = threadIdx.x & 31, ly = threadIdx.x >> 5;
#pragma unroll
  for (int i = 0; i < 32; i += 8)
    t[ly + i][lx] = kt[boff + (size_t)(r0 + ly + i) * 256 + c0 + lx];
  __syncthreads();
#pragma unroll
  for (int i = 0; i < 32; i += 8)
    ktT[boff + (size_t)(c0 + ly + i) * 2048 + r0 + lx] = t[lx][ly + i];
}

// ---------------- low-rank gate part 1: tmp[4096,16] = x @ w1 ----------------
__global__ __launch_bounds__(256) void lowrank1(
    const float* __restrict__ x, const float* __restrict__ w1,
    float* __restrict__ tmp)
{
  const int idx = blockIdx.x * 256 + threadIdx.x;
  const int m = idx >> 4, i = idx & 15;
  const float* xr = x + (size_t)m * 1024;
  float acc = 0.f;
#pragma unroll 4
  for (int kk = 0; kk < 1024; kk += 4) {
    const float4 xv = *(const float4*)(xr + kk);
    acc = fmaf(xv.x, w1[(kk + 0) * 16 + i], acc);
    acc = fmaf(xv.y, w1[(kk + 1) * 16 + i], acc);
    acc = fmaf(xv.z, w1[(kk + 2) * 16 + i], acc);
    acc = fmaf(xv.w, w1[(kk + 3) * 16 + i], acc);
  }
  tmp[idx] = acc;
}

// -------- gate cumsum -> bf16 decay factors dq = e^B, dk = e^-B; Dc = e^B_end
__global__ __launch_bounds__(256) void gate_cum(
    const float* __restrict__ tmp, const float* __restrict__ w2,
    const float* __restrict__ bias, u16* __restrict__ dq, u16* __restrict__ dk,
    float* __restrict__ Dc)
{
  __shared__ float ls_t[2048];   // tmp slice for this (b, c): 128 t x 16
  const int b = blockIdx.y >> 4, c = blockIdx.y & 15;
  const int h = blockIdx.x;
  const int i = threadIdx.x;
  const int n = h * 256 + i;
  const int bh = b * 4 + h;
  const float* tp = tmp + ((size_t)(b * 2048 + c * 128)) * 16;
#pragma unroll
  for (int r = 0; r < 8; ++r) ls_t[r * 256 + threadIdx.x] = tp[r * 256 + threadIdx.x];
  __syncthreads();
  float w2c[16];
#pragma unroll
  for (int r = 0; r < 16; ++r) w2c[r] = w2[r * 1024 + n];
  const float bn = bias[n];
  const size_t base = ((size_t)bh * 2048 + c * 128) * 256 + i;
  float B = 0.f;
  for (int t = 0; t < 128; ++t) {
    float gl = bn;
    const float* tr = ls_t + t * 16;
#pragma unroll
    for (int r = 0; r < 16; ++r) gl = fmaf(tr[r], w2c[r], gl);
    const float ls = fminf(gl, 0.f) - log1pf(expf(-fabsf(gl)));
    B += ls * 0.0625f;
    const float eB = expf(B);
    dq[base + (size_t)t * 256] = f2b(eB);
    dk[base + (size_t)t * 256] = f2b(1.f / eB);
  }
  Dc[(bh * 16 + c) * 256 + i] = expf(B);
}

// ---------------- fused projections: xb[4096,1024] @ [Wq|Wk|Wv|Wg] ----------
// q/k: decay fused, row-major. v: written TRANSPOSED directly to vT[bh][j][t].
__global__ __launch_bounds__(256) void proj_all(
    const u16* __restrict__ xb, const u16* __restrict__ WT,
    const u16* __restrict__ dq, const u16* __restrict__ dk,
    u16* __restrict__ qt, u16* __restrict__ kt,
    u16* __restrict__ vT, u16* __restrict__ gpre)
{
  __shared__ __align__(16) u16 S[24576];
  u16* As = S; u16* Bs = S + 12288;
  // XCD-chunked swizzle, n-fast within XCD
  const int id = blockIdx.x;
  const int xcd = id & 7, jb = id >> 3;
  const int m0 = (jb / 6) * 128;
  const int n0 = (xcd * 6 + (jb % 6)) * 128;
  f4v acc[4][4];
#pragma unroll
  for (int zi = 0; zi < 4; ++zi)
#pragma unroll
    for (int zj = 0; zj < 4; ++zj) acc[zi][zj] = (f4v){0.f, 0.f, 0.f, 0.f};
  gemm_core(xb + (size_t)m0 * 1024, 1024, WT + (size_t)n0 * 1024, 1024, 1024,
            As, Bs, acc);
  const int bb = m0 >> 11;              // batch (tile is within one b)
  const int t0 = m0 & 2047;
  if (n0 < 1024) {
    epi_loop(S, acc, [&](int r, int c0, s8v vv) {
      const int t = t0 + r;
      const int n = n0 + c0;
      const int bh = bb * 4 + (n >> 8);
      const size_t off = ((size_t)bh * 2048 + t) * 256 + (n & 255);
      const s8v dv = *(const s8v*)(dq + off);
      s8v o8;
#pragma unroll
      for (int e = 0; e < 8; ++e)
        o8[e] = (short)f2b(b2f((u16)vv[e]) * 0.0625f * b2f((u16)dv[e]));
      *(s8v*)(qt + off) = o8;
    });
  } else if (n0 < 2048) {
    epi_loop(S, acc, [&](int r, int c0, s8v vv) {
      const int t = t0 + r;
      const int nn = n0 + c0 - 1024;
      const int bh = bb * 4 + (nn >> 8);
      const size_t off = ((size_t)bh * 2048 + t) * 256 + (nn & 255);
      const s8v dv = *(const s8v*)(dk + off);
      s8v o8;
#pragma unroll
      for (int e = 0; e < 8; ++e)
        o8[e] = (short)f2b(b2f((u16)vv[e]) * b2f((u16)dv[e]));
      *(s8v*)(kt + off) = o8;
    });
  } else if (n0 < 4096) {
    const int nn0 = n0 - 2048;
    const int bh = bb * 4 + (nn0 >> 9);
    const int jj0 = nn0 & 511;
    epi_loop_T(S, acc, [&](int r, int c0, s8v vv) {
      // r = column offset (j), c0 = row base (t)
      *(s8v*)(vT + ((size_t)(bh * 512 + jj0 + r)) * 2048 + t0 + c0) = vv;
    });
  } else {
    epi_loop(S, acc, [&](int r, int c0, s8v vv) {
      *(s8v*)(gpre + (size_t)(m0 + r) * 2048 + (n0 + c0 - 4096)) = vv;
    });
  }
}

// ------- merged scan GEMMs: x<8 -> chunk_state tile, x==8 -> qk_causal ------
__global__ __launch_bounds__(256) void scan_gemms(
    const u16* __restrict__ vT, const u16* __restrict__ ktT,
    const u16* __restrict__ qt, const u16* __restrict__ kt,
    u16* __restrict__ UT, u16* __restrict__ Aw)
{
  __shared__ __align__(16) u16 S[24576];
  u16* As = S; u16* Bs = S + 12288;
  const int bhc = blockIdx.y, bh = bhc >> 4, c = bhc & 15;
  f4v acc[4][4];
#pragma unroll
  for (int zi = 0; zi < 4; ++zi)
#pragma unroll
    for (int zj = 0; zj < 4; ++zj) acc[zi][zj] = (f4v){0.f, 0.f, 0.f, 0.f};
  if (blockIdx.x < 8) {
    const int mt = blockIdx.x >> 1, nt = blockIdx.x & 1;
    gemm_core(vT + ((size_t)bh * 512 + mt * 128) * 2048 + c * 128, 2048,
              ktT + ((size_t)bh * 256 + nt * 128) * 2048 + c * 128, 2048, 128,
              As, Bs, acc);
    epi_loop(S, acc, [&](int r, int c0, s8v vv) {
      const int j = mt * 128 + r;
      const int i = nt * 128 + c0;
      *(s8v*)(UT + (((size_t)(bh * 512 + j)) * 16 + c) * 256 + i) = vv;
    });
  } else {
    const size_t base = ((size_t)bh * 2048 + c * 128) * 256;
    gemm_core(qt + base, 256, kt + base, 256, 256, As, Bs, acc);
    u16* Ap = Aw + (size_t)bhc * 16384;
    epi_loop(S, acc, [&](int r, int c0, s8v vv) {
      s8v o8;
#pragma unroll
      for (int e = 0; e < 8; ++e)
        o8[e] = (c0 + e <= r) ? vv[e] : (short)0;
      *(s8v*)(Ap + r * 128 + c0) = o8;
    });
  }
}

// ------ serial inter-chunk scan, in place on UT (bf16, fp32 accum) ----------
__global__ __launch_bounds__(256) void state_scan(
    u16* __restrict__ UT, const float* __restrict__ Dc)
{
  const int blk = blockIdx.x;               // 4096 = bh*512 + j
  const int bh = blk >> 9, j = blk & 511;
  const int i = threadIdx.x;
  u16* Up = UT + ((size_t)(bh * 512 + j)) * 16 * 256 + i;
  const float* Dp = Dc + bh * 16 * 256 + i;
  float Sa = 0.f;
#pragma unroll
  for (int c = 0; c < 16; ++c) {
    const float u = b2f(Up[c * 256]);
    const float d = Dp[c * 256];
    Up[c * 256] = f2b(Sa);
    Sa = d * (Sa + u);
  }
}

// -------- ob = Aw @ V + qt @ S  (per bhc, 128-col tile of HV) ---------------
__global__ __launch_bounds__(256) void intra_k(
    const u16* __restrict__ Aw, const u16* __restrict__ qt,
    const u16* __restrict__ vT, const u16* __restrict__ UT, u16* __restrict__ ob)
{
  __shared__ __align__(16) u16 S[24576];
  u16* As = S; u16* Bs = S + 12288;
  const int jt = blockIdx.x;
  const int bhc = blockIdx.y, bh = bhc >> 4, c = bhc & 15;
  f4v acc[4][4];
#pragma unroll
  for (int zi = 0; zi < 4; ++zi)
#pragma unroll
    for (int zj = 0; zj < 4; ++zj) acc[zi][zj] = (f4v){0.f, 0.f, 0.f, 0.f};
  gemm_core(Aw + (size_t)bhc * 16384, 128,
            vT + ((size_t)bh * 512 + jt * 128) * 2048 + c * 128, 2048, 128,
            As, Bs, acc);
  gemm_core(qt + ((size_t)bh * 2048 + c * 128) * 256, 256,
            UT + ((size_t)(bh * 512 + jt * 128)) * 4096 + (size_t)c * 256, 4096, 256,
            As, Bs, acc);
  const int b = bh >> 2, h = bh & 3;
  epi_loop(S, acc, [&](int r, int c0, s8v vv) {
    const int t = c * 128 + r;
    const int j = jt * 128 + c0;
    *(s8v*)(ob + ((size_t)(b * 2048 + t)) * 2048 + h * 512 + j) = vv;
  });
}

// ------- group RMSNorm (512) + SiLU gate, in place on ob (vectorized) -------
__global__ __launch_bounds__(256) void rms_silu(
    u16* __restrict__ o, const u16* __restrict__ gpre, const float* __restrict__ w)
{
  const int grp = blockIdx.x * 4 + (threadIdx.x >> 6);  // 16384 groups (b,t,h)
  const int lane = threadIdx.x & 63;
  const size_t base = (size_t)(grp >> 2) * 2048 + (grp & 3) * 512 + lane * 8;
  const s8v xv = *(const s8v*)(o + base);
  float xf[8];
  float ss = 0.f;
#pragma unroll
  for (int i = 0; i < 8; ++i) {
    xf[i] = b2f((u16)xv[i]);
    ss = fmaf(xf[i], xf[i], ss);
  }
#pragma unroll
  for (int off = 1; off < 64; off <<= 1) ss += __shfl_xor(ss, off, 64);
  const float r = rsqrtf(ss * (1.f / 512.f) + 1e-5f);
  const s8v gv = *(const s8v*)(gpre + base);
  const float4 w0 = *(const float4*)(w + lane * 8);
  const float4 w1 = *(const float4*)(w + lane * 8 + 4);
  const float wf[8] = {w0.x, w0.y, w0.z, w0.w, w1.x, w1.y, w1.z, w1.w};
  s8v o8;
#pragma unroll
  for (int i = 0; i < 8; ++i) {
    const float gp = b2f((u16)gv[i]);
    const float sig = 1.f / (1.f + expf(-gp));
    o8[i] = (short)f2b(xf[i] * r * wf[i] * gp * sig);
  }
  *(s8v*)(o + base) = o8;
}

// ---------------- final: out = ob @ Wo, split-K=2 into pout -----------------
__global__ __launch_bounds__(256) void gemm_out(
    const u16* __restrict__ ob, const u16* __restrict__ WoT,
    float* __restrict__ pout)
{
  __shared__ __align__(16) u16 S[24576];
  u16* As = S; u16* Bs = S + 12288;
  const int id = blockIdx.x;                 // 512 blocks, 64 per XCD
  const int wg = (id & 7) * 64 + (id >> 3);
  const int ks = wg >> 8;                    // K-half
  const int tt = wg & 255;
  const int m0 = (tt & 31) * 128, n0 = (tt >> 5) * 128;
  f4v acc[4][4];
#pragma unroll
  for (int zi = 0; zi < 4; ++zi)
#pragma unroll
    for (int zj = 0; zj < 4; ++zj) acc[zi][zj] = (f4v){0.f, 0.f, 0.f, 0.f};
  gemm_core(ob + (size_t)m0 * 2048 + ks * 1024, 2048,
            WoT + (size_t)n0 * 2048 + ks * 1024, 2048, 1024, As, Bs, acc);
  const int tid = threadIdx.x;
  const int ln = tid & 63, wv = tid >> 6;
  const int wr = wv >> 1, wc = wv & 1;
  float* po = pout + (size_t)ks * 4194304;
#pragma unroll
  for (int mf = 0; mf < 4; ++mf)
#pragma unroll
    for (int nf = 0; nf < 4; ++nf)
#pragma unroll
      for (int r = 0; r < 4; ++r) {
        const int m = m0 + wr * 64 + mf * 16 + ((ln >> 4) << 2) + r;
        const int n = n0 + wc * 64 + nf * 16 + (ln & 15);
        po[(size_t)m * 1024 + n] = acc[mf][nf][r];
      }
}

__global__ __launch_bounds__(256) void reduce_out(
    const float* __restrict__ p, float* __restrict__ out)
{
  const int i = blockIdx.x * 256 + threadIdx.x;   // float4 granularity
  const float4 a = ((const float4*)p)[i];
  const float4 b = ((const float4*)(p + 4194304))[i];
  ((float4*)out)[i] = make_float4(a.x + b.x, a.y + b.y, a.z + b.z, a.w + b.w);
}

extern "C" void kernel_launch(void* const* d_in, const int* in_sizes, int n_in,
                              void* d_out, int out_size, void* d_ws, size_t ws_size,
                              hipStream_t stream) {
  const float* x    = (const float*)d_in[0];
  const float* Wq   = (const float*)d_in[1];
  const float* Wk   = (const float*)d_in[2];
  const float* Wv   = (const float*)d_in[3];
  const float* Wg   = (const float*)d_in[4];
  const float* w1   = (const float*)d_in[5];
  const float* w2   = (const float*)d_in[6];
  const float* gb   = (const float*)d_in[7];
  const float* Wo   = (const float*)d_in[8];
  const float* rmsw = (const float*)d_in[9];
  float* out = (float*)d_out;

  char* W = (char*)d_ws;
  u16*   xb   = (u16*)W;   W += (size_t)8  << 20;   // [4096][1024]
  u16*   WTa  = (u16*)W;   W += (size_t)12 << 20;   // [6144][1024]
  u16*   WoT  = (u16*)W;   W += (size_t)4  << 20;   // [1024][2048]
  u16*   qt   = (u16*)W;   W += (size_t)8  << 20;   // [8][2048][256]
  u16*   kt   = (u16*)W;   W += (size_t)8  << 20;
  u16*   vT   = (u16*)W;   W += (size_t)16 << 20;   // [8][512][2048]
  u16*   ktT  = (u16*)W;   W += (size_t)8  << 20;   // [8][256][2048]
  u16*   gpre = (u16*)W;   W += (size_t)16 << 20;   // [4096][2048]
  float* tmp  = (float*)W; W += (size_t)256 << 10;  // [4096][16]
  float* Dc   = (float*)W; W += (size_t)128 << 10;  // [8][16][256]
  u16*   dq   = (u16*)W;   W += (size_t)8  << 20;   // [8][2048][256] bf16 e^B
  u16*   dk   = (u16*)W;   W += (size_t)8  << 20;   // e^-B
  u16*   UT   = (u16*)W;   W += (size_t)32 << 20;   // [8][512][16][256]
  u16*   Aw   = (u16*)W;   W += (size_t)4  << 20;   // [128][128][128]
  u16*   ob   = (u16*)W;   W += (size_t)16 << 20;   // [4096][2048]
  float* pout = (float*)W; W += (size_t)32 << 20;   // [2][4096][1024]

  // gate pipeline first (dq/dk needed by proj_all)
  hipLaunchKernelGGL(lowrank1, dim3(256), dim3(256), 0, stream, x, w1, tmp);
  hipLaunchKernelGGL(gate_cum, dim3(4, 32), dim3(256), 0, stream,
                     tmp, w2, gb, dq, dk, Dc);

  // bf16 cast of x + all weight transposes, one kernel
  hipLaunchKernelGGL(castw_all, dim3(12288), dim3(256), 0, stream,
                     x, Wq, Wk, Wv, Wg, Wo, xb, WTa, WoT);

  // fused q/k/v/g projections; v emitted transposed, decay fused
  hipLaunchKernelGGL(proj_all, dim3(1536), dim3(256), 0, stream,
                     xb, WTa, dq, dk, qt, kt, vT, gpre);

  // kt -> ktT (only remaining layout pass)
  hipLaunchKernelGGL(trans_kt, dim3(4096), dim3(256), 0, stream, kt, ktT);

  // chunked scan: (chunk_state || qk_causal) -> state_scan -> intra
  hipLaunchKernelGGL(scan_gemms, dim3(9, 128), dim3(256), 0, stream,
                     vT, ktT, qt, kt, UT, Aw);
  hipLaunchKernelGGL(state_scan, dim3(4096), dim3(256), 0, stream, UT, Dc);
  hipLaunchKernelGGL(intra_k, dim3(4, 128), dim3(256), 0, stream, Aw, qt, vT, UT, ob);

  // group RMSNorm + SiLU gate (in place), then output projection (split-K)
  hipLaunchKernelGGL(rms_silu, dim3(4096), dim3(256), 0, stream, ob, gpre, rmsw);
  hipLaunchKernelGGL(gemm_out, dim3(512), dim3(256), 0, stream, ob, WoT, pout);
  hipLaunchKernelGGL(reduce_out, dim3(4096), dim3(256), 0, stream, pout, out);
}